// Round 1
// baseline (10885.405 us; speedup 1.0000x reference)
//
#include <hip/hip_runtime.h>

#define XD 100
#define YD 100
#define ZD 16
#define VD (XD*YD*ZD)      // 160000
#define XF 200
#define YF 200
#define ZF 16
#define VF (XF*YF*ZF)      // 640000
#define NCL 18

// ---------------- prep: tinv matrices, dtau, zero GN stats ----------------
__global__ __launch_bounds__(256) void prep_kernel(const float* __restrict__ ego, const int* __restrict__ ts,
                                                   float* __restrict__ tinvs, float* __restrict__ dtau,
                                                   float* __restrict__ sums, float* __restrict__ sqs)
{
    int tid = threadIdx.x;
    for (int i = tid; i < 18*8; i += 256) { sums[i] = 0.f; sqs[i] = 0.f; }
    if (tid == 0) {
        for (int k = 0; k < 3; ++k) {
            // invert E_k via Gauss-Jordan, then tinv = inv(E_k) @ E_{k+1}
            float a[4][8];
            for (int i = 0; i < 4; ++i)
                for (int j = 0; j < 4; ++j) { a[i][j] = ego[k*16 + i*4 + j]; a[i][4+j] = (i==j) ? 1.f : 0.f; }
            for (int col = 0; col < 4; ++col) {
                int piv = col; float best = fabsf(a[col][col]);
                for (int r = col+1; r < 4; ++r) { float v = fabsf(a[r][col]); if (v > best) { best = v; piv = r; } }
                if (piv != col) for (int j = 0; j < 8; ++j) { float t = a[col][j]; a[col][j] = a[piv][j]; a[piv][j] = t; }
                float inv = 1.f / a[col][col];
                for (int j = 0; j < 8; ++j) a[col][j] *= inv;
                for (int r = 0; r < 4; ++r) {
                    if (r == col) continue;
                    float f = a[r][col];
                    for (int j = 0; j < 8; ++j) a[r][j] -= f * a[col][j];
                }
            }
            for (int i = 0; i < 4; ++i)
                for (int j = 0; j < 4; ++j) {
                    float s = 0.f;
                    for (int m = 0; m < 4; ++m) s += a[i][4+m] * ego[(k+1)*16 + m*4 + j];
                    tinvs[k*16 + i*4 + j] = s;
                }
            dtau[k] = (float)(ts[k+1] - ts[k]) * 1e-6f;
        }
    }
}

// ---------------- encoder: 3x3x3 conv stride (2,2,1) + relu (- optional sub) ----------------
// in: (18,200,200,16)  w: (64,18,3,3,3)  out chunk cb of 32 channels, (64,100,100,16)
__global__ __launch_bounds__(256) void enc_kernel(const float* __restrict__ in, const float* __restrict__ w,
                                                  const float* __restrict__ b, float* __restrict__ out,
                                                  const float* __restrict__ sub)
{
    int sp = blockIdx.x * 256 + threadIdx.x;           // 0..VD-1
    int cb = blockIdx.y;                               // 0..1 (32 out channels each)
    int zo = sp & 15; int t = sp >> 4; int yo = t % YD; int xo = t / YD;
    float acc[32];
    #pragma unroll
    for (int j = 0; j < 32; ++j) acc[j] = b[cb*32 + j];
    const float* wbase = w + cb*32*NCL*27;
    for (int ci = 0; ci < NCL; ++ci) {
        const float* inC = in + ci*VF;
        #pragma unroll
        for (int kx = 0; kx < 3; ++kx) {
            int xi = 2*xo + kx - 1; if ((unsigned)xi >= XF) continue;
            #pragma unroll
            for (int ky = 0; ky < 3; ++ky) {
                int yi = 2*yo + ky - 1; if ((unsigned)yi >= YF) continue;
                const float* row = inC + (xi*YF + yi)*ZF;
                const float* wp = wbase + ci*27 + kx*9 + ky*3;
                #pragma unroll
                for (int kz = 0; kz < 3; ++kz) {
                    int zi = zo + kz - 1; if ((unsigned)zi >= ZF) continue;
                    float v = row[zi];
                    #pragma unroll
                    for (int j = 0; j < 32; ++j) acc[j] = fmaf(v, wp[kz + j*NCL*27], acc[j]);
                }
            }
        }
    }
    float* op = out + cb*32*VD + sp;
    if (sub) {
        const float* sb = sub + cb*32*VD + sp;
        #pragma unroll
        for (int j = 0; j < 32; ++j) op[j*VD] = fmaxf(acc[j], 0.f) - sb[j*VD];
    } else {
        #pragma unroll
        for (int j = 0; j < 32; ++j) op[j*VD] = fmaxf(acc[j], 0.f);
    }
}

// ---------------- backward warp (trilinear, border clamp) for z and fast_feat[k] ----------------
__global__ __launch_bounds__(256) void warp_kernel(const float* __restrict__ z, const float* __restrict__ ff,
                                                   const float* __restrict__ tinv, float* __restrict__ zw,
                                                   float* __restrict__ fadv)
{
    int sp = blockIdx.x * 256 + threadIdx.x;
    int cb = blockIdx.y;                               // 0..7 -> 8 channels each
    int zo = sp & 15; int t = sp >> 4; int yo = t % YD; int xo = t / YD;
    float px = -40.f + (xo + 0.5f) * 0.8f;
    float py = -40.f + (yo + 0.5f) * 0.8f;
    float pz = -1.f  + (zo + 0.5f) * 0.4f;
    float qx = tinv[0]*px + tinv[1]*py + tinv[2]*pz  + tinv[3];
    float qy = tinv[4]*px + tinv[5]*py + tinv[6]*pz  + tinv[7];
    float qz = tinv[8]*px + tinv[9]*py + tinv[10]*pz + tinv[11];
    float sx = fminf(fmaxf((qx + 40.f) / 0.8f - 0.5f, 0.f), (float)(XD-1));
    float sy = fminf(fmaxf((qy + 40.f) / 0.8f - 0.5f, 0.f), (float)(YD-1));
    float sz = fminf(fmaxf((qz + 1.f)  / 0.4f - 0.5f, 0.f), (float)(ZD-1));
    float x0f = floorf(sx), y0f = floorf(sy), z0f = floorf(sz);
    int x0 = (int)x0f, y0 = (int)y0f, z0 = (int)z0f;
    int x1 = min(x0+1, XD-1), y1 = min(y0+1, YD-1), z1 = min(z0+1, ZD-1);
    float wx = sx - x0f, wy = sy - y0f, wz = sz - z0f;
    float w000 = (1.f-wx)*(1.f-wy)*(1.f-wz);
    float w100 = wx*(1.f-wy)*(1.f-wz);
    float w010 = (1.f-wx)*wy*(1.f-wz);
    float w110 = wx*wy*(1.f-wz);
    float w001 = (1.f-wx)*(1.f-wy)*wz;
    float w101 = wx*(1.f-wy)*wz;
    float w011 = (1.f-wx)*wy*wz;
    float w111 = wx*wy*wz;
    int o000 = (x0*YD + y0)*ZD + z0;
    int o100 = (x1*YD + y0)*ZD + z0;
    int o010 = (x0*YD + y1)*ZD + z0;
    int o110 = (x1*YD + y1)*ZD + z0;
    int dz = z1 - z0;
    #pragma unroll
    for (int j = 0; j < 8; ++j) {
        int c = cb*8 + j;
        const float* p = z + c*VD;
        zw[c*VD + sp] = p[o000]*w000 + p[o100]*w100 + p[o010]*w010 + p[o110]*w110
                      + p[o000+dz]*w001 + p[o100+dz]*w101 + p[o010+dz]*w011 + p[o110+dz]*w111;
        const float* q = ff + c*VD;
        fadv[c*VD + sp] = q[o000]*w000 + q[o100]*w100 + q[o010]*w010 + q[o110]*w110
                        + q[o000+dz]*w001 + q[o100+dz]*w101 + q[o010+dz]*w011 + q[o110+dz]*w111;
    }
}

// ---------------- ctrl: 1x1x1 conv over [f_t - f_adv ; dtau] -> dX (64 ch) ----------------
__global__ __launch_bounds__(256) void ctrl_kernel(const float* __restrict__ ft, const float* __restrict__ fadv,
                                                   const float* __restrict__ w, const float* __restrict__ b,
                                                   const float* __restrict__ dtau, float* __restrict__ dX)
{
    int sp = blockIdx.x * 256 + threadIdx.x;
    float dt = dtau[0];
    float acc[64];
    #pragma unroll
    for (int o = 0; o < 64; ++o) acc[o] = fmaf(w[o*65 + 64], dt, b[o]);
    for (int f = 0; f < 64; ++f) {
        float d = ft[f*VD + sp] - fadv[f*VD + sp];
        #pragma unroll
        for (int o = 0; o < 64; ++o) acc[o] = fmaf(d, w[o*65 + f], acc[o]);
    }
    #pragma unroll
    for (int o = 0; o < 64; ++o) dX[o*VD + sp] = acc[o];
}

// ---------------- g_in: 1x1x1 conv (128 -> 32) + relu; A-part may be sum of two tensors ----------------
__global__ __launch_bounds__(256) void gin_kernel(const float* __restrict__ pA, const float* __restrict__ pA2,
                                                  const float* __restrict__ pB, const float* __restrict__ w,
                                                  const float* __restrict__ b, float* __restrict__ h)
{
    int sp = blockIdx.x * 256 + threadIdx.x;
    float acc[32];
    #pragma unroll
    for (int o = 0; o < 32; ++o) acc[o] = b[o];
    if (pA2) {
        for (int c = 0; c < 64; ++c) {
            float v = pA[c*VD + sp] + pA2[c*VD + sp];
            #pragma unroll
            for (int o = 0; o < 32; ++o) acc[o] = fmaf(v, w[o*128 + c], acc[o]);
        }
    } else {
        for (int c = 0; c < 64; ++c) {
            float v = pA[c*VD + sp];
            #pragma unroll
            for (int o = 0; o < 32; ++o) acc[o] = fmaf(v, w[o*128 + c], acc[o]);
        }
    }
    for (int c = 0; c < 64; ++c) {
        float v = pB[c*VD + sp];
        #pragma unroll
        for (int o = 0; o < 32; ++o) acc[o] = fmaf(v, w[o*128 + 64 + c], acc[o]);
    }
    #pragma unroll
    for (int o = 0; o < 32; ++o) h[o*VD + sp] = fmaxf(acc[o], 0.f);
}

// ---------------- body: dilated 3x3x3 conv (32 -> 32) ----------------
__global__ __launch_bounds__(256) void body_kernel(const float* __restrict__ h, const float* __restrict__ w,
                                                   const float* __restrict__ b, float* __restrict__ c, int dil)
{
    int sp = blockIdx.x * 256 + threadIdx.x;
    int zo = sp & 15; int t = sp >> 4; int yo = t % YD; int xo = t / YD;
    float acc[32];
    #pragma unroll
    for (int o = 0; o < 32; ++o) acc[o] = b[o];
    for (int ci = 0; ci < 32; ++ci) {
        const float* hc = h + ci*VD;
        #pragma unroll
        for (int kx = 0; kx < 3; ++kx) {
            int xi = xo + (kx-1)*dil; if ((unsigned)xi >= XD) continue;
            #pragma unroll
            for (int ky = 0; ky < 3; ++ky) {
                int yi = yo + (ky-1)*dil; if ((unsigned)yi >= YD) continue;
                const float* row = hc + (xi*YD + yi)*ZD;
                const float* wp = w + ci*27 + kx*9 + ky*3;
                #pragma unroll
                for (int kz = 0; kz < 3; ++kz) {
                    int zi = zo + (kz-1)*dil; if ((unsigned)zi >= ZD) continue;
                    float v = row[zi];
                    #pragma unroll
                    for (int o = 0; o < 32; ++o) acc[o] = fmaf(v, wp[kz + o*864], acc[o]);
                }
            }
        }
    }
    #pragma unroll
    for (int o = 0; o < 32; ++o) c[o*VD + sp] = acc[o];
}

// ---------------- GroupNorm reduce: per-channel block sums -> atomic per-group stats ----------------
__global__ __launch_bounds__(256) void gnred_kernel(const float* __restrict__ c, float* __restrict__ sums,
                                                    float* __restrict__ sqs)
{
    int ch = blockIdx.y;              // 0..31
    int g = ch >> 2;                  // 8 groups of 4 channels
    const float* p = c + ch*VD;
    float s = 0.f, q = 0.f;
    for (int i = blockIdx.x*256 + threadIdx.x; i < VD; i += gridDim.x*256) {
        float v = p[i]; s += v; q = fmaf(v, v, q);
    }
    #pragma unroll
    for (int off = 32; off > 0; off >>= 1) { s += __shfl_down(s, off); q += __shfl_down(q, off); }
    __shared__ float ls[4], lq[4];
    int wid = threadIdx.x >> 6;
    if ((threadIdx.x & 63) == 0) { ls[wid] = s; lq[wid] = q; }
    __syncthreads();
    if (threadIdx.x == 0) {
        atomicAdd(&sums[g], ls[0]+ls[1]+ls[2]+ls[3]);
        atomicAdd(&sqs[g],  lq[0]+lq[1]+lq[2]+lq[3]);
    }
}

// ---------------- GroupNorm apply + relu + residual add into h ----------------
__global__ __launch_bounds__(256) void gnapply_kernel(const float* __restrict__ c, float* __restrict__ h,
                                                      const float* __restrict__ s, const float* __restrict__ bi,
                                                      const float* __restrict__ sums, const float* __restrict__ sqs)
{
    int sp = blockIdx.x*256 + threadIdx.x;
    int ch = blockIdx.y;
    int g = ch >> 2;
    const float N = 4.0f * (float)VD;
    float m = sums[g] / N;
    float var = fmaxf(sqs[g] / N - m*m, 0.f);
    float r = rsqrtf(var + 1e-5f);
    float v = fmaf((c[ch*VD + sp] - m) * r, s[ch], bi[ch]);
    h[ch*VD + sp] += fmaxf(v, 0.f);
}

// ---------------- g_out: 1x1x1 conv (32 -> 64) + tanh, * dX; mode1 fuses Heun update ----------------
__global__ __launch_bounds__(256) void gout_kernel(const float* __restrict__ h, const float* __restrict__ w,
                                                   const float* __restrict__ b, const float* __restrict__ dX,
                                                   const float* __restrict__ k1in, const float* __restrict__ zw,
                                                   float* __restrict__ outp, int mode)
{
    int sp = blockIdx.x * 256 + threadIdx.x;
    float hv[32];
    #pragma unroll
    for (int c = 0; c < 32; ++c) hv[c] = h[c*VD + sp];
    for (int o = 0; o < 64; ++o) {
        float a = b[o];
        #pragma unroll
        for (int c = 0; c < 32; ++c) a = fmaf(hv[c], w[o*32 + c], a);
        float val = tanhf(a) * dX[o*VD + sp];
        if (mode == 0) outp[o*VD + sp] = val;                                     // k1
        else outp[o*VD + sp] = zw[o*VD + sp] + 0.5f*(k1in[o*VD + sp] + val);      // new z
    }
}

// ---------------- decoder: x2 nearest upsample fused + 3x3x3 conv (64->18) + residual logits ----------------
__global__ __launch_bounds__(256) void dec_kernel(const float* __restrict__ z, const float* __restrict__ w,
                                                  const float* __restrict__ b, const float* __restrict__ fl,
                                                  float* __restrict__ out)
{
    int sp = blockIdx.x * 256 + threadIdx.x;           // 0..VF-1
    int zo = sp & 15; int t = sp >> 4; int yo = t % YF; int xo = t / YF;
    float acc[18];
    #pragma unroll
    for (int o = 0; o < 18; ++o) acc[o] = b[o];
    for (int ci = 0; ci < 64; ++ci) {
        const float* zc = z + ci*VD;
        #pragma unroll
        for (int kx = 0; kx < 3; ++kx) {
            int xi = xo + kx - 1; if ((unsigned)xi >= XF) continue;
            int xs = xi >> 1;
            #pragma unroll
            for (int ky = 0; ky < 3; ++ky) {
                int yi = yo + ky - 1; if ((unsigned)yi >= YF) continue;
                int ys = yi >> 1;
                const float* row = zc + (xs*YD + ys)*ZD;
                const float* wp = w + ci*27 + kx*9 + ky*3;
                #pragma unroll
                for (int kz = 0; kz < 3; ++kz) {
                    int zi = zo + kz - 1; if ((unsigned)zi >= ZF) continue;
                    float v = row[zi];
                    #pragma unroll
                    for (int o = 0; o < 18; ++o) acc[o] = fmaf(v, wp[kz + o*1728], acc[o]);
                }
            }
        }
    }
    #pragma unroll
    for (int o = 0; o < 18; ++o) out[o*VF + sp] = acc[o] + fl[o*VF + sp];
}

extern "C" void kernel_launch(void* const* d_in, const int* in_sizes, int n_in,
                              void* d_out, int out_size, void* d_ws, size_t ws_size,
                              hipStream_t stream)
{
    (void)in_sizes; (void)n_in; (void)out_size; (void)ws_size;
    const float* fast_logits = (const float*)d_in[0];
    const float* slow_logits = (const float*)d_in[1];
    const float* ego         = (const float*)d_in[2];
    const float* fenc_w      = (const float*)d_in[3];
    const float* fenc_b      = (const float*)d_in[4];
    const float* senc_w      = (const float*)d_in[5];
    const float* senc_b      = (const float*)d_in[6];
    const float* ctrl_w      = (const float*)d_in[7];
    const float* ctrl_b      = (const float*)d_in[8];
    const float* gin_w       = (const float*)d_in[9];
    const float* gin_b       = (const float*)d_in[10];
    const float* gbody_w     = (const float*)d_in[11];
    const float* gbody_b     = (const float*)d_in[12];
    const float* ggn_s       = (const float*)d_in[13];
    const float* ggn_b       = (const float*)d_in[14];
    const float* goutw       = (const float*)d_in[15];
    const float* goutb       = (const float*)d_in[16];
    const float* dec_w       = (const float*)d_in[17];
    const float* dec_b       = (const float*)d_in[18];
    const int*   ts          = (const int*)d_in[19];
    float* out = (float*)d_out;

    float* ws = (float*)d_ws;
    size_t off = 0;
    float* slotA = ws + off; off += (size_t)64*VD;   // rolling fast_feat slot
    float* slotB = ws + off; off += (size_t)64*VD;
    float* zbuf  = ws + off; off += (size_t)64*VD;
    float* zw    = ws + off; off += (size_t)64*VD;
    float* fadv  = ws + off; off += (size_t)64*VD;   // reused as k1 after g_out #1
    float* dX    = ws + off; off += (size_t)64*VD;
    float* hbuf  = ws + off; off += (size_t)32*VD;
    float* cbuf  = ws + off; off += (size_t)32*VD;
    float* tinvs = ws + off; off += 48;
    float* dtau  = ws + off; off += 4;
    float* sums  = ws + off; off += 144;
    float* sqs   = ws + off; off += 144;
    float* k1 = fadv;

    dim3 gsp(VD/256);

    prep_kernel<<<1, 256, 0, stream>>>(ego, ts, tinvs, dtau, sums, sqs);

    // encode frames 0,1 and slow (slow fused with z = slow_feat - fast_feat[0])
    enc_kernel<<<dim3(VD/256, 2), 256, 0, stream>>>(fast_logits + (size_t)0*NCL*VF, fenc_w, fenc_b, slotA, nullptr);
    enc_kernel<<<dim3(VD/256, 2), 256, 0, stream>>>(fast_logits + (size_t)1*NCL*VF, fenc_w, fenc_b, slotB, nullptr);
    enc_kernel<<<dim3(VD/256, 2), 256, 0, stream>>>(slow_logits, senc_w, senc_b, zbuf, slotA);

    int use = 0;
    for (int k = 0; k < 3; ++k) {
        float* fk = (k & 1) ? slotB : slotA;   // fast_feat[k]
        float* ft = (k & 1) ? slotA : slotB;   // fast_feat[k+1]
        warp_kernel<<<dim3(VD/256, 8), 256, 0, stream>>>(zbuf, fk, tinvs + k*16, zw, fadv);
        ctrl_kernel<<<gsp, 256, 0, stream>>>(ft, fadv, ctrl_w, ctrl_b, dtau + k, dX);
        // func_g #1 on [z_w ; f_adv]
        gin_kernel<<<gsp, 256, 0, stream>>>(zw, nullptr, fadv, gin_w, gin_b, hbuf);
        for (int i = 0; i < 3; ++i) {
            body_kernel<<<gsp, 256, 0, stream>>>(hbuf, gbody_w + (size_t)i*32*32*27, gbody_b + i*32, cbuf, 1+i);
            gnred_kernel<<<dim3(20, 32), 256, 0, stream>>>(cbuf, sums + use*8, sqs + use*8);
            gnapply_kernel<<<dim3(VD/256, 32), 256, 0, stream>>>(cbuf, hbuf, ggn_s + i*32, ggn_b + i*32,
                                                                 sums + use*8, sqs + use*8);
            ++use;
        }
        gout_kernel<<<gsp, 256, 0, stream>>>(hbuf, goutw, goutb, dX, nullptr, nullptr, k1, 0);
        // func_g #2 on [z_w + k1 ; f_t]
        gin_kernel<<<gsp, 256, 0, stream>>>(zw, k1, ft, gin_w, gin_b, hbuf);
        for (int i = 0; i < 3; ++i) {
            body_kernel<<<gsp, 256, 0, stream>>>(hbuf, gbody_w + (size_t)i*32*32*27, gbody_b + i*32, cbuf, 1+i);
            gnred_kernel<<<dim3(20, 32), 256, 0, stream>>>(cbuf, sums + use*8, sqs + use*8);
            gnapply_kernel<<<dim3(VD/256, 32), 256, 0, stream>>>(cbuf, hbuf, ggn_s + i*32, ggn_b + i*32,
                                                                 sums + use*8, sqs + use*8);
            ++use;
        }
        gout_kernel<<<gsp, 256, 0, stream>>>(hbuf, goutw, goutb, dX, k1, zw, zbuf, 1);
        // rolling-encode the next needed frame into the freed slot
        if (k == 0) enc_kernel<<<dim3(VD/256, 2), 256, 0, stream>>>(fast_logits + (size_t)2*NCL*VF, fenc_w, fenc_b, slotA, nullptr);
        if (k == 1) enc_kernel<<<dim3(VD/256, 2), 256, 0, stream>>>(fast_logits + (size_t)3*NCL*VF, fenc_w, fenc_b, slotB, nullptr);
    }

    dec_kernel<<<VF/256, 256, 0, stream>>>(zbuf, dec_w, dec_b, fast_logits + (size_t)3*NCL*VF, out);
}

// Round 2
// 9339.623 us; speedup vs baseline: 1.1655x; 1.1655x over previous
//
#include <hip/hip_runtime.h>

#define XD 100
#define YD 100
#define ZD 16
#define VD (XD*YD*ZD)      // 160000
#define XF 200
#define YF 200
#define ZF 16
#define VF (XF*YF*ZF)      // 640000
#define NCL 18

// ---------------- prep: tinv matrices, dtau, zero GN stats ----------------
__global__ __launch_bounds__(256) void prep_kernel(const float* __restrict__ ego, const int* __restrict__ ts,
                                                   float* __restrict__ tinvs, float* __restrict__ dtau,
                                                   float* __restrict__ sums, float* __restrict__ sqs)
{
    int tid = threadIdx.x;
    for (int i = tid; i < 18*8; i += 256) { sums[i] = 0.f; sqs[i] = 0.f; }
    if (tid == 0) {
        for (int k = 0; k < 3; ++k) {
            float a[4][8];
            for (int i = 0; i < 4; ++i)
                for (int j = 0; j < 4; ++j) { a[i][j] = ego[k*16 + i*4 + j]; a[i][4+j] = (i==j) ? 1.f : 0.f; }
            for (int col = 0; col < 4; ++col) {
                int piv = col; float best = fabsf(a[col][col]);
                for (int r = col+1; r < 4; ++r) { float v = fabsf(a[r][col]); if (v > best) { best = v; piv = r; } }
                if (piv != col) for (int j = 0; j < 8; ++j) { float t = a[col][j]; a[col][j] = a[piv][j]; a[piv][j] = t; }
                float inv = 1.f / a[col][col];
                for (int j = 0; j < 8; ++j) a[col][j] *= inv;
                for (int r = 0; r < 4; ++r) {
                    if (r == col) continue;
                    float f = a[r][col];
                    for (int j = 0; j < 8; ++j) a[r][j] -= f * a[col][j];
                }
            }
            for (int i = 0; i < 4; ++i)
                for (int j = 0; j < 4; ++j) {
                    float s = 0.f;
                    for (int m = 0; m < 4; ++m) s += a[i][4+m] * ego[(k+1)*16 + m*4 + j];
                    tinvs[k*16 + i*4 + j] = s;
                }
            dtau[k] = (float)(ts[k+1] - ts[k]) * 1e-6f;
        }
    }
}

// ---------------- weight transposes ----------------
// 3x3x3 conv: in[o][ci][kx][ky][kz] -> out[((ci*9+kx*3+ky)*O + o)*3 + kz]
__global__ __launch_bounds__(256) void t3_kernel(const float* __restrict__ in, float* __restrict__ out, int O, int CI)
{
    int n = O*CI*27;
    for (int idx = blockIdx.x*256 + threadIdx.x; idx < n; idx += gridDim.x*256) {
        int o = idx / (CI*27);
        int r = idx - o*CI*27;
        int ci = r / 27;
        int t = r - ci*27;
        int kxy = t / 3;
        int kz = t - kxy*3;
        out[((ci*9 + kxy)*O + o)*3 + kz] = in[idx];
    }
}
// 1x1x1 conv: in[o][c] -> out[c*O + o]
__global__ __launch_bounds__(256) void t1_kernel(const float* __restrict__ in, float* __restrict__ out, int O, int C)
{
    int n = O*C;
    for (int idx = blockIdx.x*256 + threadIdx.x; idx < n; idx += gridDim.x*256) {
        int o = idx / C;
        int c = idx - o*C;
        out[c*O + o] = in[idx];
    }
}

// ---------------- encoder v2: 3x3x3 stride(2,2,1) + relu (- optional sub) ----------------
// thread = (xo,yo) column, NO=4 out channels per y-block. wt layout: [(ci*9+t)*64 + o]*3 + kz
__global__ __launch_bounds__(64) void enc2_kernel(const float* __restrict__ in, const float* __restrict__ wt,
                                                  const float* __restrict__ b, float* __restrict__ out,
                                                  const float* __restrict__ sub)
{
    int sp = blockIdx.x*64 + threadIdx.x;
    if (sp >= XD*YD) return;
    int xo = sp / YD, yo = sp - xo*YD;
    int oc = blockIdx.y * 4;
    float acc[4][16];
    #pragma unroll
    for (int o = 0; o < 4; ++o) {
        float bv = b[oc+o];
        #pragma unroll
        for (int z = 0; z < 16; ++z) acc[o][z] = bv;
    }
    float c18[18];
    c18[0] = 0.f; c18[17] = 0.f;
    for (int ci = 0; ci < NCL; ++ci) {
        const float* inC = in + (size_t)ci*VF;
        #pragma unroll
        for (int kx = 0; kx < 3; ++kx) {
            int xi = 2*xo + kx - 1;
            bool vx = (unsigned)xi < XF;
            #pragma unroll
            for (int ky = 0; ky < 3; ++ky) {
                int yi = 2*yo + ky - 1;
                bool v = vx && ((unsigned)yi < YF);
                const float* col = inC + ((v ? xi : 0)*YF + (v ? yi : 0))*ZF;
                const float4* cq = (const float4*)col;
                float4 q0 = cq[0], q1 = cq[1], q2 = cq[2], q3 = cq[3];
                float m = v ? 1.f : 0.f;
                c18[1]=q0.x*m;  c18[2]=q0.y*m;  c18[3]=q0.z*m;  c18[4]=q0.w*m;
                c18[5]=q1.x*m;  c18[6]=q1.y*m;  c18[7]=q1.z*m;  c18[8]=q1.w*m;
                c18[9]=q2.x*m;  c18[10]=q2.y*m; c18[11]=q2.z*m; c18[12]=q2.w*m;
                c18[13]=q3.x*m; c18[14]=q3.y*m; c18[15]=q3.z*m; c18[16]=q3.w*m;
                const float* wp = wt + (size_t)((ci*9 + kx*3 + ky)*64 + oc)*3;
                const float4* wq = (const float4*)wp;
                float4 w0 = wq[0], w1 = wq[1], w2 = wq[2];
                float wr[12];
                wr[0]=w0.x; wr[1]=w0.y; wr[2]=w0.z; wr[3]=w0.w;
                wr[4]=w1.x; wr[5]=w1.y; wr[6]=w1.z; wr[7]=w1.w;
                wr[8]=w2.x; wr[9]=w2.y; wr[10]=w2.z; wr[11]=w2.w;
                #pragma unroll
                for (int o = 0; o < 4; ++o)
                    #pragma unroll
                    for (int kz = 0; kz < 3; ++kz) {
                        float wv = wr[o*3+kz];
                        #pragma unroll
                        for (int z = 0; z < 16; ++z)
                            acc[o][z] = fmaf(c18[z+kz], wv, acc[o][z]);
                    }
            }
        }
    }
    int base = (xo*YD + yo)*ZD;
    #pragma unroll
    for (int o = 0; o < 4; ++o) {
        float* op = out + (size_t)(oc+o)*VD + base;
        if (sub) {
            const float* sb = sub + (size_t)(oc+o)*VD + base;
            #pragma unroll
            for (int q = 0; q < 4; ++q) {
                float4 s = ((const float4*)sb)[q];
                float4 r;
                r.x = fmaxf(acc[o][4*q+0], 0.f) - s.x;
                r.y = fmaxf(acc[o][4*q+1], 0.f) - s.y;
                r.z = fmaxf(acc[o][4*q+2], 0.f) - s.z;
                r.w = fmaxf(acc[o][4*q+3], 0.f) - s.w;
                ((float4*)op)[q] = r;
            }
        } else {
            #pragma unroll
            for (int q = 0; q < 4; ++q) {
                float4 r;
                r.x = fmaxf(acc[o][4*q+0], 0.f);
                r.y = fmaxf(acc[o][4*q+1], 0.f);
                r.z = fmaxf(acc[o][4*q+2], 0.f);
                r.w = fmaxf(acc[o][4*q+3], 0.f);
                ((float4*)op)[q] = r;
            }
        }
    }
}

// ---------------- body v2: dilated 3x3x3 (32->32), NO=4, full z column ----------------
template<int DIL>
__global__ __launch_bounds__(64) void body2_kernel(const float* __restrict__ h, const float* __restrict__ wt,
                                                   const float* __restrict__ b, float* __restrict__ cout)
{
    int sp = blockIdx.x*64 + threadIdx.x;
    if (sp >= XD*YD) return;
    int xo = sp / YD, yo = sp - xo*YD;
    int oc = blockIdx.y * 4;
    float acc[4][16];
    #pragma unroll
    for (int o = 0; o < 4; ++o) {
        float bv = b[oc+o];
        #pragma unroll
        for (int z = 0; z < 16; ++z) acc[o][z] = bv;
    }
    float c22[22];
    #pragma unroll
    for (int i = 0; i < 22; ++i) c22[i] = 0.f;
    for (int ci = 0; ci < 32; ++ci) {
        const float* hc = h + (size_t)ci*VD;
        #pragma unroll
        for (int kx = 0; kx < 3; ++kx) {
            int xi = xo + (kx-1)*DIL;
            bool vx = (unsigned)xi < XD;
            #pragma unroll
            for (int ky = 0; ky < 3; ++ky) {
                int yi = yo + (ky-1)*DIL;
                bool v = vx && ((unsigned)yi < YD);
                const float* col = hc + ((v ? xi : 0)*YD + (v ? yi : 0))*ZD;
                const float4* cq = (const float4*)col;
                float4 q0 = cq[0], q1 = cq[1], q2 = cq[2], q3 = cq[3];
                float m = v ? 1.f : 0.f;
                c22[3]=q0.x*m;  c22[4]=q0.y*m;  c22[5]=q0.z*m;  c22[6]=q0.w*m;
                c22[7]=q1.x*m;  c22[8]=q1.y*m;  c22[9]=q1.z*m;  c22[10]=q1.w*m;
                c22[11]=q2.x*m; c22[12]=q2.y*m; c22[13]=q2.z*m; c22[14]=q2.w*m;
                c22[15]=q3.x*m; c22[16]=q3.y*m; c22[17]=q3.z*m; c22[18]=q3.w*m;
                const float* wp = wt + (size_t)((ci*9 + kx*3 + ky)*32 + oc)*3;
                const float4* wq = (const float4*)wp;
                float4 w0 = wq[0], w1 = wq[1], w2 = wq[2];
                float wr[12];
                wr[0]=w0.x; wr[1]=w0.y; wr[2]=w0.z; wr[3]=w0.w;
                wr[4]=w1.x; wr[5]=w1.y; wr[6]=w1.z; wr[7]=w1.w;
                wr[8]=w2.x; wr[9]=w2.y; wr[10]=w2.z; wr[11]=w2.w;
                #pragma unroll
                for (int o = 0; o < 4; ++o)
                    #pragma unroll
                    for (int kz = 0; kz < 3; ++kz) {
                        float wv = wr[o*3+kz];
                        #pragma unroll
                        for (int z = 0; z < 16; ++z)
                            acc[o][z] = fmaf(c22[3 + z + (kz-1)*DIL], wv, acc[o][z]);
                    }
            }
        }
    }
    int base = (xo*YD + yo)*ZD;
    #pragma unroll
    for (int o = 0; o < 4; ++o) {
        float* op = cout + (size_t)(oc+o)*VD + base;
        #pragma unroll
        for (int q = 0; q < 4; ++q)
            ((float4*)op)[q] = make_float4(acc[o][4*q], acc[o][4*q+1], acc[o][4*q+2], acc[o][4*q+3]);
    }
}

// ---------------- decoder v2: x2 nearest upsample fused + 3x3x3 (64->18) + residual ----------------
// thread = (xo,yo) full-res column, NO=6 out channels per y-block (3 blocks)
__global__ __launch_bounds__(64) void dec2_kernel(const float* __restrict__ z, const float* __restrict__ wt,
                                                  const float* __restrict__ b, const float* __restrict__ fl,
                                                  float* __restrict__ out)
{
    int sp = blockIdx.x*64 + threadIdx.x;
    if (sp >= XF*YF) return;
    int xo = sp / YF, yo = sp - xo*YF;
    int oc = blockIdx.y * 6;
    float acc[6][16];
    #pragma unroll
    for (int o = 0; o < 6; ++o) {
        float bv = b[oc+o];
        #pragma unroll
        for (int zz = 0; zz < 16; ++zz) acc[o][zz] = bv;
    }
    float c18[18];
    c18[0] = 0.f; c18[17] = 0.f;
    for (int ci = 0; ci < 64; ++ci) {
        const float* zc = z + (size_t)ci*VD;
        #pragma unroll
        for (int kx = 0; kx < 3; ++kx) {
            int xi = xo + kx - 1;
            bool vx = (unsigned)xi < XF;
            int xs = (vx ? xi : 0) >> 1;
            #pragma unroll
            for (int ky = 0; ky < 3; ++ky) {
                int yi = yo + ky - 1;
                bool v = vx && ((unsigned)yi < YF);
                int ys = (v ? yi : 0) >> 1;
                const float* col = zc + (xs*YD + ys)*ZD;
                const float4* cq = (const float4*)col;
                float4 q0 = cq[0], q1 = cq[1], q2 = cq[2], q3 = cq[3];
                float m = v ? 1.f : 0.f;
                c18[1]=q0.x*m;  c18[2]=q0.y*m;  c18[3]=q0.z*m;  c18[4]=q0.w*m;
                c18[5]=q1.x*m;  c18[6]=q1.y*m;  c18[7]=q1.z*m;  c18[8]=q1.w*m;
                c18[9]=q2.x*m;  c18[10]=q2.y*m; c18[11]=q2.z*m; c18[12]=q2.w*m;
                c18[13]=q3.x*m; c18[14]=q3.y*m; c18[15]=q3.z*m; c18[16]=q3.w*m;
                const float* wp = wt + (size_t)((ci*9 + kx*3 + ky)*18 + oc)*3;
                float wr[18];
                #pragma unroll
                for (int j = 0; j < 18; ++j) wr[j] = wp[j];
                #pragma unroll
                for (int o = 0; o < 6; ++o)
                    #pragma unroll
                    for (int kz = 0; kz < 3; ++kz) {
                        float wv = wr[o*3+kz];
                        #pragma unroll
                        for (int zz = 0; zz < 16; ++zz)
                            acc[o][zz] = fmaf(c18[zz+kz], wv, acc[o][zz]);
                    }
            }
        }
    }
    int base = (xo*YF + yo)*ZF;
    #pragma unroll
    for (int o = 0; o < 6; ++o) {
        float* op = out + (size_t)(oc+o)*VF + base;
        const float* fp = fl + (size_t)(oc+o)*VF + base;
        #pragma unroll
        for (int q = 0; q < 4; ++q) {
            float4 f = ((const float4*)fp)[q];
            ((float4*)op)[q] = make_float4(acc[o][4*q]+f.x, acc[o][4*q+1]+f.y,
                                           acc[o][4*q+2]+f.z, acc[o][4*q+3]+f.w);
        }
    }
}

// ---------------- warp (trilinear, border clamp) ----------------
__global__ __launch_bounds__(256) void warp_kernel(const float* __restrict__ z, const float* __restrict__ ff,
                                                   const float* __restrict__ tinv, float* __restrict__ zw,
                                                   float* __restrict__ fadv)
{
    int sp = blockIdx.x * 256 + threadIdx.x;
    int cb = blockIdx.y;
    int zo = sp & 15; int t = sp >> 4; int yo = t % YD; int xo = t / YD;
    float px = -40.f + (xo + 0.5f) * 0.8f;
    float py = -40.f + (yo + 0.5f) * 0.8f;
    float pz = -1.f  + (zo + 0.5f) * 0.4f;
    float qx = tinv[0]*px + tinv[1]*py + tinv[2]*pz  + tinv[3];
    float qy = tinv[4]*px + tinv[5]*py + tinv[6]*pz  + tinv[7];
    float qz = tinv[8]*px + tinv[9]*py + tinv[10]*pz + tinv[11];
    float sx = fminf(fmaxf((qx + 40.f) / 0.8f - 0.5f, 0.f), (float)(XD-1));
    float sy = fminf(fmaxf((qy + 40.f) / 0.8f - 0.5f, 0.f), (float)(YD-1));
    float sz = fminf(fmaxf((qz + 1.f)  / 0.4f - 0.5f, 0.f), (float)(ZD-1));
    float x0f = floorf(sx), y0f = floorf(sy), z0f = floorf(sz);
    int x0 = (int)x0f, y0 = (int)y0f, z0 = (int)z0f;
    int x1 = min(x0+1, XD-1), y1 = min(y0+1, YD-1), z1 = min(z0+1, ZD-1);
    float wx = sx - x0f, wy = sy - y0f, wz = sz - z0f;
    float w000 = (1.f-wx)*(1.f-wy)*(1.f-wz);
    float w100 = wx*(1.f-wy)*(1.f-wz);
    float w010 = (1.f-wx)*wy*(1.f-wz);
    float w110 = wx*wy*(1.f-wz);
    float w001 = (1.f-wx)*(1.f-wy)*wz;
    float w101 = wx*(1.f-wy)*wz;
    float w011 = (1.f-wx)*wy*wz;
    float w111 = wx*wy*wz;
    int o000 = (x0*YD + y0)*ZD + z0;
    int o100 = (x1*YD + y0)*ZD + z0;
    int o010 = (x0*YD + y1)*ZD + z0;
    int o110 = (x1*YD + y1)*ZD + z0;
    int dz = z1 - z0;
    #pragma unroll
    for (int j = 0; j < 8; ++j) {
        int c = cb*8 + j;
        const float* p = z + (size_t)c*VD;
        zw[(size_t)c*VD + sp] = p[o000]*w000 + p[o100]*w100 + p[o010]*w010 + p[o110]*w110
                      + p[o000+dz]*w001 + p[o100+dz]*w101 + p[o010+dz]*w011 + p[o110+dz]*w111;
        const float* q = ff + (size_t)c*VD;
        fadv[(size_t)c*VD + sp] = q[o000]*w000 + q[o100]*w100 + q[o010]*w010 + q[o110]*w110
                        + q[o000+dz]*w001 + q[o100+dz]*w101 + q[o010+dz]*w011 + q[o110+dz]*w111;
    }
}

// ---------------- ctrl v2: 1x1x1 [f_t - f_adv ; dtau] -> dX. NO=16, 4 voxels/thread ----------------
__global__ __launch_bounds__(64) void ctrl2_kernel(const float* __restrict__ ft, const float* __restrict__ fadv,
                                                   const float* __restrict__ wt, const float* __restrict__ b,
                                                   const float* __restrict__ dtau, float* __restrict__ dX)
{
    int sp4 = blockIdx.x*64 + threadIdx.x;
    if (sp4 >= VD/4) return;
    int oc = blockIdx.y * 16;
    float dt = dtau[0];
    float acc[16][4];
    #pragma unroll
    for (int j = 0; j < 16; ++j) {
        float a0 = fmaf(wt[64*64 + oc + j], dt, b[oc+j]);
        acc[j][0]=a0; acc[j][1]=a0; acc[j][2]=a0; acc[j][3]=a0;
    }
    for (int f = 0; f < 64; ++f) {
        float4 va = ((const float4*)(ft  + (size_t)f*VD))[sp4];
        float4 vb = ((const float4*)(fadv+ (size_t)f*VD))[sp4];
        float d0=va.x-vb.x, d1=va.y-vb.y, d2=va.z-vb.z, d3=va.w-vb.w;
        const float* wp = wt + f*64 + oc;
        float wr[16];
        #pragma unroll
        for (int j = 0; j < 16; ++j) wr[j] = wp[j];
        #pragma unroll
        for (int j = 0; j < 16; ++j) {
            acc[j][0] = fmaf(d0, wr[j], acc[j][0]);
            acc[j][1] = fmaf(d1, wr[j], acc[j][1]);
            acc[j][2] = fmaf(d2, wr[j], acc[j][2]);
            acc[j][3] = fmaf(d3, wr[j], acc[j][3]);
        }
    }
    #pragma unroll
    for (int j = 0; j < 16; ++j)
        ((float4*)(dX + (size_t)(oc+j)*VD))[sp4] = make_float4(acc[j][0], acc[j][1], acc[j][2], acc[j][3]);
}

// ---------------- g_in v2: 1x1x1 (128 -> 32) + relu. NO=16, 4 voxels/thread ----------------
__global__ __launch_bounds__(64) void gin2_kernel(const float* __restrict__ pA, const float* __restrict__ pA2,
                                                  const float* __restrict__ pB, const float* __restrict__ wt,
                                                  const float* __restrict__ b, float* __restrict__ h)
{
    int sp4 = blockIdx.x*64 + threadIdx.x;
    if (sp4 >= VD/4) return;
    int oc = blockIdx.y * 16;
    float acc[16][4];
    #pragma unroll
    for (int j = 0; j < 16; ++j) {
        float bv = b[oc+j];
        acc[j][0]=bv; acc[j][1]=bv; acc[j][2]=bv; acc[j][3]=bv;
    }
    for (int c = 0; c < 64; ++c) {
        float4 v = ((const float4*)(pA + (size_t)c*VD))[sp4];
        if (pA2) {
            float4 v2 = ((const float4*)(pA2 + (size_t)c*VD))[sp4];
            v.x += v2.x; v.y += v2.y; v.z += v2.z; v.w += v2.w;
        }
        const float* wp = wt + c*32 + oc;
        float wr[16];
        #pragma unroll
        for (int j = 0; j < 16; ++j) wr[j] = wp[j];
        #pragma unroll
        for (int j = 0; j < 16; ++j) {
            acc[j][0] = fmaf(v.x, wr[j], acc[j][0]);
            acc[j][1] = fmaf(v.y, wr[j], acc[j][1]);
            acc[j][2] = fmaf(v.z, wr[j], acc[j][2]);
            acc[j][3] = fmaf(v.w, wr[j], acc[j][3]);
        }
    }
    for (int c = 0; c < 64; ++c) {
        float4 v = ((const float4*)(pB + (size_t)c*VD))[sp4];
        const float* wp = wt + (64+c)*32 + oc;
        float wr[16];
        #pragma unroll
        for (int j = 0; j < 16; ++j) wr[j] = wp[j];
        #pragma unroll
        for (int j = 0; j < 16; ++j) {
            acc[j][0] = fmaf(v.x, wr[j], acc[j][0]);
            acc[j][1] = fmaf(v.y, wr[j], acc[j][1]);
            acc[j][2] = fmaf(v.z, wr[j], acc[j][2]);
            acc[j][3] = fmaf(v.w, wr[j], acc[j][3]);
        }
    }
    #pragma unroll
    for (int j = 0; j < 16; ++j)
        ((float4*)(h + (size_t)(oc+j)*VD))[sp4] = make_float4(fmaxf(acc[j][0],0.f), fmaxf(acc[j][1],0.f),
                                                              fmaxf(acc[j][2],0.f), fmaxf(acc[j][3],0.f));
}

// ---------------- GroupNorm reduce ----------------
__global__ __launch_bounds__(256) void gnred_kernel(const float* __restrict__ c, float* __restrict__ sums,
                                                    float* __restrict__ sqs)
{
    int ch = blockIdx.y;
    int g = ch >> 2;
    const float* p = c + (size_t)ch*VD;
    float s = 0.f, q = 0.f;
    for (int i = blockIdx.x*256 + threadIdx.x; i < VD; i += gridDim.x*256) {
        float v = p[i]; s += v; q = fmaf(v, v, q);
    }
    #pragma unroll
    for (int off = 32; off > 0; off >>= 1) { s += __shfl_down(s, off); q += __shfl_down(q, off); }
    __shared__ float ls[4], lq[4];
    int wid = threadIdx.x >> 6;
    if ((threadIdx.x & 63) == 0) { ls[wid] = s; lq[wid] = q; }
    __syncthreads();
    if (threadIdx.x == 0) {
        atomicAdd(&sums[g], ls[0]+ls[1]+ls[2]+ls[3]);
        atomicAdd(&sqs[g],  lq[0]+lq[1]+lq[2]+lq[3]);
    }
}

// ---------------- GroupNorm apply + relu + residual add into h ----------------
__global__ __launch_bounds__(256) void gnapply_kernel(const float* __restrict__ c, float* __restrict__ h,
                                                      const float* __restrict__ s, const float* __restrict__ bi,
                                                      const float* __restrict__ sums, const float* __restrict__ sqs)
{
    int sp = blockIdx.x*256 + threadIdx.x;
    int ch = blockIdx.y;
    int g = ch >> 2;
    const float N = 4.0f * (float)VD;
    float m = sums[g] / N;
    float var = fmaxf(sqs[g] / N - m*m, 0.f);
    float r = rsqrtf(var + 1e-5f);
    float v = fmaf((c[(size_t)ch*VD + sp] - m) * r, s[ch], bi[ch]);
    h[(size_t)ch*VD + sp] += fmaxf(v, 0.f);
}

// ---------------- g_out v2: 1x1x1 (32 -> 64) + tanh*dX; mode1 fuses Heun. NO=16, 4 voxels ----------------
__global__ __launch_bounds__(64) void gout2_kernel(const float* __restrict__ h, const float* __restrict__ wt,
                                                   const float* __restrict__ b, const float* __restrict__ dX,
                                                   const float* __restrict__ k1in, const float* __restrict__ zw,
                                                   float* __restrict__ outp, int mode)
{
    int sp4 = blockIdx.x*64 + threadIdx.x;
    if (sp4 >= VD/4) return;
    int oc = blockIdx.y * 16;
    float acc[16][4];
    #pragma unroll
    for (int j = 0; j < 16; ++j) {
        float bv = b[oc+j];
        acc[j][0]=bv; acc[j][1]=bv; acc[j][2]=bv; acc[j][3]=bv;
    }
    for (int c = 0; c < 32; ++c) {
        float4 v = ((const float4*)(h + (size_t)c*VD))[sp4];
        const float* wp = wt + c*64 + oc;
        float wr[16];
        #pragma unroll
        for (int j = 0; j < 16; ++j) wr[j] = wp[j];
        #pragma unroll
        for (int j = 0; j < 16; ++j) {
            acc[j][0] = fmaf(v.x, wr[j], acc[j][0]);
            acc[j][1] = fmaf(v.y, wr[j], acc[j][1]);
            acc[j][2] = fmaf(v.z, wr[j], acc[j][2]);
            acc[j][3] = fmaf(v.w, wr[j], acc[j][3]);
        }
    }
    #pragma unroll
    for (int j = 0; j < 16; ++j) {
        float4 dx = ((const float4*)(dX + (size_t)(oc+j)*VD))[sp4];
        float4 val;
        val.x = tanhf(acc[j][0]) * dx.x;
        val.y = tanhf(acc[j][1]) * dx.y;
        val.z = tanhf(acc[j][2]) * dx.z;
        val.w = tanhf(acc[j][3]) * dx.w;
        if (mode == 0) {
            ((float4*)(outp + (size_t)(oc+j)*VD))[sp4] = val;
        } else {
            float4 k1 = ((const float4*)(k1in + (size_t)(oc+j)*VD))[sp4];
            float4 zv = ((const float4*)(zw   + (size_t)(oc+j)*VD))[sp4];
            val.x = zv.x + 0.5f*(k1.x + val.x);
            val.y = zv.y + 0.5f*(k1.y + val.y);
            val.z = zv.z + 0.5f*(k1.z + val.z);
            val.w = zv.w + 0.5f*(k1.w + val.w);
            ((float4*)(outp + (size_t)(oc+j)*VD))[sp4] = val;
        }
    }
}

extern "C" void kernel_launch(void* const* d_in, const int* in_sizes, int n_in,
                              void* d_out, int out_size, void* d_ws, size_t ws_size,
                              hipStream_t stream)
{
    (void)in_sizes; (void)n_in; (void)out_size; (void)ws_size;
    const float* fast_logits = (const float*)d_in[0];
    const float* slow_logits = (const float*)d_in[1];
    const float* ego         = (const float*)d_in[2];
    const float* fenc_w      = (const float*)d_in[3];
    const float* fenc_b      = (const float*)d_in[4];
    const float* senc_w      = (const float*)d_in[5];
    const float* senc_b      = (const float*)d_in[6];
    const float* ctrl_w      = (const float*)d_in[7];
    const float* ctrl_b      = (const float*)d_in[8];
    const float* gin_w       = (const float*)d_in[9];
    const float* gin_b       = (const float*)d_in[10];
    const float* gbody_w     = (const float*)d_in[11];
    const float* gbody_b     = (const float*)d_in[12];
    const float* ggn_s       = (const float*)d_in[13];
    const float* ggn_b       = (const float*)d_in[14];
    const float* goutw       = (const float*)d_in[15];
    const float* goutb       = (const float*)d_in[16];
    const float* dec_w       = (const float*)d_in[17];
    const float* dec_b       = (const float*)d_in[18];
    const int*   ts          = (const int*)d_in[19];
    float* out = (float*)d_out;

    float* ws = (float*)d_ws;
    size_t off = 0;
    float* slotA = ws + off; off += (size_t)64*VD;
    float* slotB = ws + off; off += (size_t)64*VD;
    float* zbuf  = ws + off; off += (size_t)64*VD;
    float* zw    = ws + off; off += (size_t)64*VD;
    float* fadv  = ws + off; off += (size_t)64*VD;   // reused as k1
    float* dX    = ws + off; off += (size_t)64*VD;
    float* hbuf  = ws + off; off += (size_t)32*VD;
    float* cbuf  = ws + off; off += (size_t)32*VD;
    float* tinvs = ws + off; off += 48;
    float* dtau  = ws + off; off += 4;
    float* sums  = ws + off; off += 144;
    float* sqs   = ws + off; off += 144;
    float* fencT = ws + off; off += 64*18*27;
    float* sencT = ws + off; off += 64*18*27;
    float* bodyT = ws + off; off += 3*32*32*27;
    float* decT  = ws + off; off += 18*64*27;
    float* ginT  = ws + off; off += 32*128;
    float* goutT = ws + off; off += 64*32;
    float* ctrlT = ws + off; off += 64*65;
    float* k1 = fadv;

    prep_kernel<<<1, 256, 0, stream>>>(ego, ts, tinvs, dtau, sums, sqs);
    t3_kernel<<<122, 256, 0, stream>>>(fenc_w, fencT, 64, 18);
    t3_kernel<<<122, 256, 0, stream>>>(senc_w, sencT, 64, 18);
    for (int i = 0; i < 3; ++i)
        t3_kernel<<<108, 256, 0, stream>>>(gbody_w + (size_t)i*32*32*27, bodyT + (size_t)i*32*32*27, 32, 32);
    t3_kernel<<<122, 256, 0, stream>>>(dec_w, decT, 18, 64);
    t1_kernel<<<16, 256, 0, stream>>>(gin_w, ginT, 32, 128);
    t1_kernel<<<8, 256, 0, stream>>>(goutw, goutT, 64, 32);
    t1_kernel<<<17, 256, 0, stream>>>(ctrl_w, ctrlT, 64, 65);

    dim3 encg(157, 16);    // 10000 cols / 64, 16 o-chunks of 4
    dim3 bodyg(157, 8);    // 8 o-chunks of 4
    dim3 decg(625, 3);     // 40000 cols / 64, 3 o-chunks of 6
    dim3 c1g(625, 2);      // gin: 40000 quads / 64, 2 o-chunks of 16
    dim3 c1g4(625, 4);     // ctrl/gout: 4 o-chunks of 16

    enc2_kernel<<<encg, 64, 0, stream>>>(fast_logits + (size_t)0*NCL*VF, fencT, fenc_b, slotA, nullptr);
    enc2_kernel<<<encg, 64, 0, stream>>>(fast_logits + (size_t)1*NCL*VF, fencT, fenc_b, slotB, nullptr);
    enc2_kernel<<<encg, 64, 0, stream>>>(slow_logits, sencT, senc_b, zbuf, slotA);

    int use = 0;
    for (int k = 0; k < 3; ++k) {
        float* fk = (k & 1) ? slotB : slotA;
        float* ft = (k & 1) ? slotA : slotB;
        warp_kernel<<<dim3(VD/256, 8), 256, 0, stream>>>(zbuf, fk, tinvs + k*16, zw, fadv);
        ctrl2_kernel<<<c1g4, 64, 0, stream>>>(ft, fadv, ctrlT, ctrl_b, dtau + k, dX);
        gin2_kernel<<<c1g, 64, 0, stream>>>(zw, nullptr, fadv, ginT, gin_b, hbuf);
        for (int i = 0; i < 3; ++i) {
            if (i == 0) body2_kernel<1><<<bodyg, 64, 0, stream>>>(hbuf, bodyT + (size_t)0*32*32*27, gbody_b + 0, cbuf);
            if (i == 1) body2_kernel<2><<<bodyg, 64, 0, stream>>>(hbuf, bodyT + (size_t)1*32*32*27, gbody_b + 32, cbuf);
            if (i == 2) body2_kernel<3><<<bodyg, 64, 0, stream>>>(hbuf, bodyT + (size_t)2*32*32*27, gbody_b + 64, cbuf);
            gnred_kernel<<<dim3(20, 32), 256, 0, stream>>>(cbuf, sums + use*8, sqs + use*8);
            gnapply_kernel<<<dim3(VD/256, 32), 256, 0, stream>>>(cbuf, hbuf, ggn_s + i*32, ggn_b + i*32,
                                                                 sums + use*8, sqs + use*8);
            ++use;
        }
        gout2_kernel<<<c1g4, 64, 0, stream>>>(hbuf, goutT, goutb, dX, nullptr, nullptr, k1, 0);
        gin2_kernel<<<c1g, 64, 0, stream>>>(zw, k1, ft, ginT, gin_b, hbuf);
        for (int i = 0; i < 3; ++i) {
            if (i == 0) body2_kernel<1><<<bodyg, 64, 0, stream>>>(hbuf, bodyT + (size_t)0*32*32*27, gbody_b + 0, cbuf);
            if (i == 1) body2_kernel<2><<<bodyg, 64, 0, stream>>>(hbuf, bodyT + (size_t)1*32*32*27, gbody_b + 32, cbuf);
            if (i == 2) body2_kernel<3><<<bodyg, 64, 0, stream>>>(hbuf, bodyT + (size_t)2*32*32*27, gbody_b + 64, cbuf);
            gnred_kernel<<<dim3(20, 32), 256, 0, stream>>>(cbuf, sums + use*8, sqs + use*8);
            gnapply_kernel<<<dim3(VD/256, 32), 256, 0, stream>>>(cbuf, hbuf, ggn_s + i*32, ggn_b + i*32,
                                                                 sums + use*8, sqs + use*8);
            ++use;
        }
        gout2_kernel<<<c1g4, 64, 0, stream>>>(hbuf, goutT, goutb, dX, k1, zw, zbuf, 1);
        if (k == 0) enc2_kernel<<<encg, 64, 0, stream>>>(fast_logits + (size_t)2*NCL*VF, fencT, fenc_b, slotA, nullptr);
        if (k == 1) enc2_kernel<<<encg, 64, 0, stream>>>(fast_logits + (size_t)3*NCL*VF, fencT, fenc_b, slotB, nullptr);
    }

    dec2_kernel<<<decg, 64, 0, stream>>>(zbuf, decT, dec_b, fast_logits + (size_t)3*NCL*VF, out);
}

// Round 4
// 5414.382 us; speedup vs baseline: 2.0105x; 1.7250x over previous
//
#include <hip/hip_runtime.h>

#define XD 100
#define YD 100
#define ZD 16
#define VD (XD*YD*ZD)      // 160000
#define XF 200
#define YF 200
#define ZF 16
#define VF (XF*YF*ZF)      // 640000
#define NCL 18

typedef unsigned int uint32;
typedef unsigned short ushort16;
typedef __attribute__((ext_vector_type(8))) short short8v;
typedef __attribute__((ext_vector_type(4))) float float4v;

__device__ __forceinline__ ushort16 f2bf(float f) {
    uint32 u = __float_as_uint(f);
    u += 0x7fffu + ((u >> 16) & 1u);          // RNE
    return (ushort16)(u >> 16);
}
__device__ __forceinline__ float bf2f(uint32 h) { return __uint_as_float(h << 16); }
__device__ __forceinline__ uint32 pk2(float a, float b) {
    return (uint32)f2bf(a) | ((uint32)f2bf(b) << 16);
}

// ---------------- prep: tinv matrices, dtau, zero GN stats ----------------
__global__ __launch_bounds__(256) void prep_kernel(const float* __restrict__ ego, const int* __restrict__ ts,
                                                   float* __restrict__ tinvs, float* __restrict__ dtau,
                                                   float* __restrict__ sums, float* __restrict__ sqs)
{
    int tid = threadIdx.x;
    for (int i = tid; i < 18*8; i += 256) { sums[i] = 0.f; sqs[i] = 0.f; }
    if (tid == 0) {
        for (int k = 0; k < 3; ++k) {
            float a[4][8];
            for (int i = 0; i < 4; ++i)
                for (int j = 0; j < 4; ++j) { a[i][j] = ego[k*16 + i*4 + j]; a[i][4+j] = (i==j) ? 1.f : 0.f; }
            for (int col = 0; col < 4; ++col) {
                int piv = col; float best = fabsf(a[col][col]);
                for (int r = col+1; r < 4; ++r) { float v = fabsf(a[r][col]); if (v > best) { best = v; piv = r; } }
                if (piv != col) for (int j = 0; j < 8; ++j) { float t = a[col][j]; a[col][j] = a[piv][j]; a[piv][j] = t; }
                float inv = 1.f / a[col][col];
                for (int j = 0; j < 8; ++j) a[col][j] *= inv;
                for (int r = 0; r < 4; ++r) {
                    if (r == col) continue;
                    float f = a[r][col];
                    for (int j = 0; j < 8; ++j) a[r][j] -= f * a[col][j];
                }
            }
            for (int i = 0; i < 4; ++i)
                for (int j = 0; j < 4; ++j) {
                    float s = 0.f;
                    for (int m = 0; m < 4; ++m) s += a[i][4+m] * ego[(k+1)*16 + m*4 + j];
                    tinvs[k*16 + i*4 + j] = s;
                }
            dtau[k] = (float)(ts[k+1] - ts[k]) * 1e-6f;
        }
    }
}

// ---------------- weight transposes (enc fp32 path + 1x1 convs) ----------------
__global__ __launch_bounds__(256) void t3_kernel(const float* __restrict__ in, float* __restrict__ out, int O, int CI)
{
    int n = O*CI*27;
    for (int idx = blockIdx.x*256 + threadIdx.x; idx < n; idx += gridDim.x*256) {
        int o = idx / (CI*27);
        int r = idx - o*CI*27;
        int ci = r / 27;
        int t = r - ci*27;
        int kxy = t / 3;
        int kz = t - kxy*3;
        out[((ci*9 + kxy)*O + o)*3 + kz] = in[idx];
    }
}
__global__ __launch_bounds__(256) void t1_kernel(const float* __restrict__ in, float* __restrict__ out, int O, int C)
{
    int n = O*C;
    for (int idx = blockIdx.x*256 + threadIdx.x; idx < n; idx += gridDim.x*256) {
        int o = idx / C;
        int c = idx - o*C;
        out[c*O + o] = in[idx];
    }
}

// ---------------- A-fragment packers (bf16) ----------------
// body: w fp32 [32o][32ci][27t] -> pack[((t*2+f)*64+l)*8+j], set i in blockIdx.y
__global__ __launch_bounds__(256) void packA_body_kernel(const float* __restrict__ w, ushort16* __restrict__ out)
{
    int i = blockIdx.y;
    const float* wi = w + (size_t)i*32*32*27;
    ushort16* oi = out + (size_t)i*27648;
    int idx = blockIdx.x*256 + threadIdx.x;
    if (idx >= 27648) return;
    int j = idx & 7;
    int l = (idx >> 3) & 63;
    int f = (idx >> 9) & 1;
    int t = idx >> 10;
    int oc = f*16 + (l & 15);
    int ci = (l >> 4)*8 + j;
    oi[idx] = f2bf(wi[((size_t)oc*32 + ci)*27 + t]);
}
// dec: w fp32 [18o][64ci][27t] -> pack[(((t*2+ks)*2+f)*64+l)*8+j], oc>=18 -> 0
__global__ __launch_bounds__(256) void packA_dec_kernel(const float* __restrict__ w, ushort16* __restrict__ out)
{
    int idx = blockIdx.x*256 + threadIdx.x;
    if (idx >= 55296) return;
    int j = idx & 7;
    int l = (idx >> 3) & 63;
    int f = (idx >> 9) & 1;
    int ks = (idx >> 10) & 1;
    int t = idx >> 11;
    int oc = f*16 + (l & 15);
    int ci = ks*32 + (l >> 4)*8 + j;
    out[idx] = (oc < 18) ? f2bf(w[((size_t)oc*64 + ci)*27 + t]) : (ushort16)0;
}

// ---------------- encoder (fp32, unchanged) ----------------
__global__ __launch_bounds__(64) void enc2_kernel(const float* __restrict__ in, const float* __restrict__ wt,
                                                  const float* __restrict__ b, float* __restrict__ out,
                                                  const float* __restrict__ sub)
{
    int sp = blockIdx.x*64 + threadIdx.x;
    if (sp >= XD*YD) return;
    int xo = sp / YD, yo = sp - xo*YD;
    int oc = blockIdx.y * 4;
    float acc[4][16];
    #pragma unroll
    for (int o = 0; o < 4; ++o) {
        float bv = b[oc+o];
        #pragma unroll
        for (int z = 0; z < 16; ++z) acc[o][z] = bv;
    }
    float c18[18];
    c18[0] = 0.f; c18[17] = 0.f;
    for (int ci = 0; ci < NCL; ++ci) {
        const float* inC = in + (size_t)ci*VF;
        #pragma unroll
        for (int kx = 0; kx < 3; ++kx) {
            int xi = 2*xo + kx - 1;
            bool vx = (unsigned)xi < XF;
            #pragma unroll
            for (int ky = 0; ky < 3; ++ky) {
                int yi = 2*yo + ky - 1;
                bool v = vx && ((unsigned)yi < YF);
                const float* col = inC + ((v ? xi : 0)*YF + (v ? yi : 0))*ZF;
                const float4* cq = (const float4*)col;
                float4 q0 = cq[0], q1 = cq[1], q2 = cq[2], q3 = cq[3];
                float m = v ? 1.f : 0.f;
                c18[1]=q0.x*m;  c18[2]=q0.y*m;  c18[3]=q0.z*m;  c18[4]=q0.w*m;
                c18[5]=q1.x*m;  c18[6]=q1.y*m;  c18[7]=q1.z*m;  c18[8]=q1.w*m;
                c18[9]=q2.x*m;  c18[10]=q2.y*m; c18[11]=q2.z*m; c18[12]=q2.w*m;
                c18[13]=q3.x*m; c18[14]=q3.y*m; c18[15]=q3.z*m; c18[16]=q3.w*m;
                const float* wp = wt + (size_t)((ci*9 + kx*3 + ky)*64 + oc)*3;
                const float4* wq = (const float4*)wp;
                float4 w0 = wq[0], w1 = wq[1], w2 = wq[2];
                float wr[12];
                wr[0]=w0.x; wr[1]=w0.y; wr[2]=w0.z; wr[3]=w0.w;
                wr[4]=w1.x; wr[5]=w1.y; wr[6]=w1.z; wr[7]=w1.w;
                wr[8]=w2.x; wr[9]=w2.y; wr[10]=w2.z; wr[11]=w2.w;
                #pragma unroll
                for (int o = 0; o < 4; ++o)
                    #pragma unroll
                    for (int kz = 0; kz < 3; ++kz) {
                        float wv = wr[o*3+kz];
                        #pragma unroll
                        for (int z = 0; z < 16; ++z)
                            acc[o][z] = fmaf(c18[z+kz], wv, acc[o][z]);
                    }
            }
        }
    }
    int base = (xo*YD + yo)*ZD;
    #pragma unroll
    for (int o = 0; o < 4; ++o) {
        float* op = out + (size_t)(oc+o)*VD + base;
        if (sub) {
            const float* sb = sub + (size_t)(oc+o)*VD + base;
            #pragma unroll
            for (int q = 0; q < 4; ++q) {
                float4 s = ((const float4*)sb)[q];
                float4 r;
                r.x = fmaxf(acc[o][4*q+0], 0.f) - s.x;
                r.y = fmaxf(acc[o][4*q+1], 0.f) - s.y;
                r.z = fmaxf(acc[o][4*q+2], 0.f) - s.z;
                r.w = fmaxf(acc[o][4*q+3], 0.f) - s.w;
                ((float4*)op)[q] = r;
            }
        } else {
            #pragma unroll
            for (int q = 0; q < 4; ++q) {
                float4 r;
                r.x = fmaxf(acc[o][4*q+0], 0.f);
                r.y = fmaxf(acc[o][4*q+1], 0.f);
                r.z = fmaxf(acc[o][4*q+2], 0.f);
                r.w = fmaxf(acc[o][4*q+3], 0.f);
                ((float4*)op)[q] = r;
            }
        }
    }
}

// ---------------- body v3: dilated 3x3x3 (32->32) via MFMA bf16 ----------------
// h_cl: [voxel][32ci] bf16. Wave: 4 (x,y) columns, out 32oc x 16z each.
template<int DIL>
__global__ __launch_bounds__(256) void body3_kernel(const ushort16* __restrict__ hcl,
                                                    const ushort16* __restrict__ apack,
                                                    const float* __restrict__ b,
                                                    ushort16* __restrict__ ccl)
{
    int wid = threadIdx.x >> 6, lane = threadIdx.x & 63;
    int colbase = (blockIdx.x*4 + wid)*4;
    int zl = lane & 15, kgrp = lane >> 4;
    int ci0 = kgrp*8;
    float4v acc[4][2];
    #pragma unroll
    for (int r = 0; r < 4; ++r) {
        float b0 = b[kgrp*4 + r], b1 = b[16 + kgrp*4 + r];
        #pragma unroll
        for (int c = 0; c < 4; ++c) { acc[c][0][r] = b0; acc[c][1][r] = b1; }
    }
    int xo[4], yo[4];
    #pragma unroll
    for (int c = 0; c < 4; ++c) { int col = colbase + c; xo[c] = col / YD; yo[c] = col - xo[c]*YD; }
    const short8v* ap = (const short8v*)apack;
    const short8v zz = {0,0,0,0,0,0,0,0};
    #pragma unroll
    for (int kx = 0; kx < 3; ++kx)
    #pragma unroll
    for (int ky = 0; ky < 3; ++ky)
    #pragma unroll
    for (int kz = 0; kz < 3; ++kz) {
        const int t = (kx*3 + ky)*3 + kz;
        short8v a0 = ap[(t*2 + 0)*64 + lane];
        short8v a1 = ap[(t*2 + 1)*64 + lane];
        int zi = zl + (kz - 1)*DIL;
        bool vz = (unsigned)zi < 16u;
        int zc = vz ? zi : 0;
        #pragma unroll
        for (int c = 0; c < 4; ++c) {
            int xi = xo[c] + (kx - 1)*DIL;
            int yi = yo[c] + (ky - 1)*DIL;
            if ((unsigned)xi >= (unsigned)XD || (unsigned)yi >= (unsigned)YD) continue;
            short8v bv = *(const short8v*)((const ushort16*)hcl + ((size_t)((xi*YD + yi)*16 + zc))*32 + ci0);
            bv = vz ? bv : zz;
            acc[c][0] = __builtin_amdgcn_mfma_f32_16x16x32_bf16(a0, bv, acc[c][0], 0, 0, 0);
            acc[c][1] = __builtin_amdgcn_mfma_f32_16x16x32_bf16(a1, bv, acc[c][1], 0, 0, 0);
        }
    }
    #pragma unroll
    for (int c = 0; c < 4; ++c) {
        size_t sp = (size_t)(colbase + c)*16 + zl;
        #pragma unroll
        for (int f = 0; f < 2; ++f) {
            uint2 pk;
            pk.x = pk2(acc[c][f][0], acc[c][f][1]);
            pk.y = pk2(acc[c][f][2], acc[c][f][3]);
            *(uint2*)((ushort16*)ccl + sp*32 + f*16 + kgrp*4) = pk;
        }
    }
}

// ---------------- dec v3: upsample + 3x3x3 (64->18) via MFMA bf16 + residual ----------------
__global__ __launch_bounds__(256) void dec3_kernel(const ushort16* __restrict__ zcl,
                                                   const ushort16* __restrict__ apack,
                                                   const float* __restrict__ b,
                                                   const float* __restrict__ fl,
                                                   float* __restrict__ out)
{
    int wid = threadIdx.x >> 6, lane = threadIdx.x & 63;
    int colbase = (blockIdx.x*4 + wid)*4;      // full-res columns
    int zl = lane & 15, kgrp = lane >> 4;
    int ci0 = kgrp*8;
    float4v acc[4][2];
    #pragma unroll
    for (int r = 0; r < 4; ++r) {
        int oc0 = kgrp*4 + r, oc1 = 16 + kgrp*4 + r;
        float b0 = b[oc0];
        float b1 = (oc1 < 18) ? b[oc1] : 0.f;
        #pragma unroll
        for (int c = 0; c < 4; ++c) { acc[c][0][r] = b0; acc[c][1][r] = b1; }
    }
    int xo[4], yo[4];
    #pragma unroll
    for (int c = 0; c < 4; ++c) { int col = colbase + c; xo[c] = col / YF; yo[c] = col - xo[c]*YF; }
    const short8v* ap = (const short8v*)apack;
    const short8v zz = {0,0,0,0,0,0,0,0};
    #pragma unroll
    for (int kx = 0; kx < 3; ++kx)
    #pragma unroll
    for (int ky = 0; ky < 3; ++ky)
    #pragma unroll
    for (int kz = 0; kz < 3; ++kz) {
        const int t = (kx*3 + ky)*3 + kz;
        short8v a00 = ap[((t*2 + 0)*2 + 0)*64 + lane];
        short8v a01 = ap[((t*2 + 0)*2 + 1)*64 + lane];
        short8v a10 = ap[((t*2 + 1)*2 + 0)*64 + lane];
        short8v a11 = ap[((t*2 + 1)*2 + 1)*64 + lane];
        int zi = zl + (kz - 1);
        bool vz = (unsigned)zi < 16u;
        int zc = vz ? zi : 0;
        #pragma unroll
        for (int c = 0; c < 4; ++c) {
            int xi = xo[c] + (kx - 1);
            int yi = yo[c] + (ky - 1);
            if ((unsigned)xi >= (unsigned)XF || (unsigned)yi >= (unsigned)YF) continue;
            int xs = xi >> 1, ys = yi >> 1;
            size_t voxoff = ((size_t)((xs*YD + ys)*16 + zc))*64;
            short8v bv0 = *(const short8v*)((const ushort16*)zcl + voxoff + ci0);
            short8v bv1 = *(const short8v*)((const ushort16*)zcl + voxoff + 32 + ci0);
            bv0 = vz ? bv0 : zz;
            bv1 = vz ? bv1 : zz;
            acc[c][0] = __builtin_amdgcn_mfma_f32_16x16x32_bf16(a00, bv0, acc[c][0], 0, 0, 0);
            acc[c][1] = __builtin_amdgcn_mfma_f32_16x16x32_bf16(a01, bv0, acc[c][1], 0, 0, 0);
            acc[c][0] = __builtin_amdgcn_mfma_f32_16x16x32_bf16(a10, bv1, acc[c][0], 0, 0, 0);
            acc[c][1] = __builtin_amdgcn_mfma_f32_16x16x32_bf16(a11, bv1, acc[c][1], 0, 0, 0);
        }
    }
    #pragma unroll
    for (int c = 0; c < 4; ++c) {
        size_t sp = (size_t)(colbase + c)*16 + zl;
        #pragma unroll
        for (int r = 0; r < 4; ++r) {
            int oc = kgrp*4 + r;
            out[(size_t)oc*VF + sp] = acc[c][0][r] + fl[(size_t)oc*VF + sp];
        }
        if (kgrp == 0) {
            #pragma unroll
            for (int r = 0; r < 2; ++r) {
                int oc = 16 + r;
                out[(size_t)oc*VF + sp] = acc[c][1][r] + fl[(size_t)oc*VF + sp];
            }
        }
    }
}

// ---------------- planar fp32 (64ch) -> channels-last bf16 ----------------
__global__ __launch_bounds__(64) void tocl64_kernel(const float* __restrict__ z, ushort16* __restrict__ zcl)
{
    int v = blockIdx.x*64 + threadIdx.x;
    uint32 r[32];
    #pragma unroll
    for (int p = 0; p < 32; ++p)
        r[p] = pk2(z[(size_t)(2*p)*VD + v], z[(size_t)(2*p + 1)*VD + v]);
    uint4* op = (uint4*)((ushort16*)zcl + (size_t)v*64);
    #pragma unroll
    for (int q = 0; q < 8; ++q)
        op[q] = make_uint4(r[4*q], r[4*q+1], r[4*q+2], r[4*q+3]);
}

// ---------------- warp (trilinear, border clamp) ----------------
__global__ __launch_bounds__(256) void warp_kernel(const float* __restrict__ z, const float* __restrict__ ff,
                                                   const float* __restrict__ tinv, float* __restrict__ zw,
                                                   float* __restrict__ fadv)
{
    int sp = blockIdx.x * 256 + threadIdx.x;
    int cb = blockIdx.y;
    int zo = sp & 15; int t = sp >> 4; int yo = t % YD; int xo = t / YD;
    float px = -40.f + (xo + 0.5f) * 0.8f;
    float py = -40.f + (yo + 0.5f) * 0.8f;
    float pz = -1.f  + (zo + 0.5f) * 0.4f;
    float qx = tinv[0]*px + tinv[1]*py + tinv[2]*pz  + tinv[3];
    float qy = tinv[4]*px + tinv[5]*py + tinv[6]*pz  + tinv[7];
    float qz = tinv[8]*px + tinv[9]*py + tinv[10]*pz + tinv[11];
    float sx = fminf(fmaxf((qx + 40.f) / 0.8f - 0.5f, 0.f), (float)(XD-1));
    float sy = fminf(fmaxf((qy + 40.f) / 0.8f - 0.5f, 0.f), (float)(YD-1));
    float sz = fminf(fmaxf((qz + 1.f)  / 0.4f - 0.5f, 0.f), (float)(ZD-1));
    float x0f = floorf(sx), y0f = floorf(sy), z0f = floorf(sz);
    int x0 = (int)x0f, y0 = (int)y0f, z0 = (int)z0f;
    int x1 = min(x0+1, XD-1), y1 = min(y0+1, YD-1), z1 = min(z0+1, ZD-1);
    float wx = sx - x0f, wy = sy - y0f, wz = sz - z0f;
    float w000 = (1.f-wx)*(1.f-wy)*(1.f-wz);
    float w100 = wx*(1.f-wy)*(1.f-wz);
    float w010 = (1.f-wx)*wy*(1.f-wz);
    float w110 = wx*wy*(1.f-wz);
    float w001 = (1.f-wx)*(1.f-wy)*wz;
    float w101 = wx*(1.f-wy)*wz;
    float w011 = (1.f-wx)*wy*wz;
    float w111 = wx*wy*wz;
    int o000 = (x0*YD + y0)*ZD + z0;
    int o100 = (x1*YD + y0)*ZD + z0;
    int o010 = (x0*YD + y1)*ZD + z0;
    int o110 = (x1*YD + y1)*ZD + z0;
    int dz = z1 - z0;
    #pragma unroll
    for (int j = 0; j < 8; ++j) {
        int c = cb*8 + j;
        const float* p = z + (size_t)c*VD;
        zw[(size_t)c*VD + sp] = p[o000]*w000 + p[o100]*w100 + p[o010]*w010 + p[o110]*w110
                      + p[o000+dz]*w001 + p[o100+dz]*w101 + p[o010+dz]*w011 + p[o110+dz]*w111;
        const float* q = ff + (size_t)c*VD;
        fadv[(size_t)c*VD + sp] = q[o000]*w000 + q[o100]*w100 + q[o010]*w010 + q[o110]*w110
                        + q[o000+dz]*w001 + q[o100+dz]*w101 + q[o010+dz]*w011 + q[o110+dz]*w111;
    }
}

// ---------------- ctrl: 1x1x1 [f_t - f_adv ; dtau] -> dX (planar fp32) ----------------
__global__ __launch_bounds__(64) void ctrl2_kernel(const float* __restrict__ ft, const float* __restrict__ fadv,
                                                   const float* __restrict__ wt, const float* __restrict__ b,
                                                   const float* __restrict__ dtau, float* __restrict__ dX)
{
    int sp4 = blockIdx.x*64 + threadIdx.x;
    if (sp4 >= VD/4) return;
    int oc = blockIdx.y * 16;
    float dt = dtau[0];
    float acc[16][4];
    #pragma unroll
    for (int j = 0; j < 16; ++j) {
        float a0 = fmaf(wt[64*64 + oc + j], dt, b[oc+j]);
        acc[j][0]=a0; acc[j][1]=a0; acc[j][2]=a0; acc[j][3]=a0;
    }
    for (int f = 0; f < 64; ++f) {
        float4 va = ((const float4*)(ft  + (size_t)f*VD))[sp4];
        float4 vb = ((const float4*)(fadv+ (size_t)f*VD))[sp4];
        float d0=va.x-vb.x, d1=va.y-vb.y, d2=va.z-vb.z, d3=va.w-vb.w;
        const float* wp = wt + f*64 + oc;
        float wr[16];
        #pragma unroll
        for (int j = 0; j < 16; ++j) wr[j] = wp[j];
        #pragma unroll
        for (int j = 0; j < 16; ++j) {
            acc[j][0] = fmaf(d0, wr[j], acc[j][0]);
            acc[j][1] = fmaf(d1, wr[j], acc[j][1]);
            acc[j][2] = fmaf(d2, wr[j], acc[j][2]);
            acc[j][3] = fmaf(d3, wr[j], acc[j][3]);
        }
    }
    #pragma unroll
    for (int j = 0; j < 16; ++j)
        ((float4*)(dX + (size_t)(oc+j)*VD))[sp4] = make_float4(acc[j][0], acc[j][1], acc[j][2], acc[j][3]);
}

// ---------------- g_in v3: 1x1x1 (128->32)+relu, planar fp32 in -> CL bf16 out ----------------
__global__ __launch_bounds__(256) void gin3_kernel(const float* __restrict__ pA, const float* __restrict__ pA2,
                                                   const float* __restrict__ pB, const float* __restrict__ wt,
                                                   const float* __restrict__ b, ushort16* __restrict__ hcl)
{
    int v = blockIdx.x*256 + threadIdx.x;
    float acc[32];
    #pragma unroll
    for (int o = 0; o < 32; ++o) acc[o] = b[o];
    for (int c = 0; c < 64; ++c) {
        float x = pA[(size_t)c*VD + v];
        if (pA2) x += pA2[(size_t)c*VD + v];
        const float* wp = wt + c*32;
        #pragma unroll
        for (int o = 0; o < 32; ++o) acc[o] = fmaf(x, wp[o], acc[o]);
    }
    for (int c = 0; c < 64; ++c) {
        float x = pB[(size_t)c*VD + v];
        const float* wp = wt + (64 + c)*32;
        #pragma unroll
        for (int o = 0; o < 32; ++o) acc[o] = fmaf(x, wp[o], acc[o]);
    }
    uint32 r[16];
    #pragma unroll
    for (int o = 0; o < 16; ++o)
        r[o] = pk2(fmaxf(acc[2*o], 0.f), fmaxf(acc[2*o+1], 0.f));
    uint4* hp = (uint4*)((ushort16*)hcl + (size_t)v*32);
    #pragma unroll
    for (int q = 0; q < 4; ++q)
        hp[q] = make_uint4(r[4*q], r[4*q+1], r[4*q+2], r[4*q+3]);
}

// ---------------- GN reduce over CL bf16 c ----------------
__global__ __launch_bounds__(256) void gnred3_kernel(const ushort16* __restrict__ ccl, float* __restrict__ sums,
                                                     float* __restrict__ sqs)
{
    int t = threadIdx.x;
    int ci = t & 31;
    int slot = t >> 5;              // 0..7
    const ushort16* p = (const ushort16*)ccl;
    float s = 0.f, q = 0.f;
    for (int v = blockIdx.x*8 + slot; v < VD; v += gridDim.x*8) {
        float x = bf2f(p[(size_t)v*32 + ci]);
        s += x; q = fmaf(x, x, q);
    }
    s += __shfl_down(s, 32); q += __shfl_down(q, 32);
    __shared__ float ls[4][32], lq[4][32];
    int w = t >> 6;
    if ((t & 63) < 32) { ls[w][t & 31] = s; lq[w][t & 31] = q; }
    __syncthreads();
    if (t < 32) {
        float st = ls[0][t] + ls[1][t] + ls[2][t] + ls[3][t];
        float qt = lq[0][t] + lq[1][t] + lq[2][t] + lq[3][t];
        atomicAdd(&sums[t >> 2], st);
        atomicAdd(&sqs[t >> 2], qt);
    }
}

// ---------------- GN apply + relu + residual (CL bf16 in-place on h) ----------------
__global__ __launch_bounds__(256) void gnapply3_kernel(const ushort16* __restrict__ ccl, ushort16* __restrict__ hcl,
                                                       const float* __restrict__ s, const float* __restrict__ bi,
                                                       const float* __restrict__ sums, const float* __restrict__ sqs)
{
    int v = blockIdx.x*256 + threadIdx.x;
    float m8[8], r8[8];
    const float invN = 1.f / (4.f * (float)VD);
    #pragma unroll
    for (int g = 0; g < 8; ++g) {
        float mm = sums[g] * invN;
        float vv = fmaxf(sqs[g] * invN - mm*mm, 0.f);
        m8[g] = mm; r8[g] = rsqrtf(vv + 1e-5f);
    }
    const uint4* cp = (const uint4*)((const ushort16*)ccl + (size_t)v*32);
    uint4* hp = (uint4*)((ushort16*)hcl + (size_t)v*32);
    #pragma unroll
    for (int q = 0; q < 4; ++q) {
        uint4 cu = cp[q];
        uint4 hu = hp[q];
        uint32 cw[4] = {cu.x, cu.y, cu.z, cu.w};
        uint32 hw[4] = {hu.x, hu.y, hu.z, hu.w};
        uint32 rw[4];
        #pragma unroll
        for (int p = 0; p < 4; ++p) {
            int c0 = q*8 + p*2;
            float cv0 = bf2f(cw[p] & 0xffffu), cv1 = bf2f(cw[p] >> 16);
            float hv0 = bf2f(hw[p] & 0xffffu), hv1 = bf2f(hw[p] >> 16);
            int g0 = c0 >> 2, g1 = (c0 + 1) >> 2;
            float n0 = fmaf((cv0 - m8[g0]) * r8[g0], s[c0], bi[c0]);
            float n1 = fmaf((cv1 - m8[g1]) * r8[g1], s[c0+1], bi[c0+1]);
            rw[p] = pk2(hv0 + fmaxf(n0, 0.f), hv1 + fmaxf(n1, 0.f));
        }
        hp[q] = make_uint4(rw[0], rw[1], rw[2], rw[3]);
    }
}

// ---------------- g_out v3: 1x1x1 (32->64)+tanh*dX; mode1 fuses Heun. CL bf16 h in ----------------
__global__ __launch_bounds__(256) void gout3_kernel(const ushort16* __restrict__ hcl, const float* __restrict__ wt,
                                                    const float* __restrict__ b, const float* __restrict__ dX,
                                                    const float* __restrict__ k1in, const float* __restrict__ zw,
                                                    float* __restrict__ outp, int mode)
{
    int v = blockIdx.x*256 + threadIdx.x;
    float hv[32];
    const uint4* hp = (const uint4*)((const ushort16*)hcl + (size_t)v*32);
    #pragma unroll
    for (int q = 0; q < 4; ++q) {
        uint4 u = hp[q];
        uint32 uw[4] = {u.x, u.y, u.z, u.w};
        #pragma unroll
        for (int p = 0; p < 4; ++p) {
            hv[q*8 + 2*p]     = bf2f(uw[p] & 0xffffu);
            hv[q*8 + 2*p + 1] = bf2f(uw[p] >> 16);
        }
    }
    float acc[64];
    #pragma unroll
    for (int o = 0; o < 64; ++o) acc[o] = b[o];
    for (int c = 0; c < 32; ++c) {
        const float* wp = wt + c*64;
        float x = hv[c];
        #pragma unroll
        for (int o = 0; o < 64; ++o) acc[o] = fmaf(x, wp[o], acc[o]);
    }
    if (mode == 0) {
        #pragma unroll
        for (int o = 0; o < 64; ++o)
            outp[(size_t)o*VD + v] = tanhf(acc[o]) * dX[(size_t)o*VD + v];
    } else {
        #pragma unroll
        for (int o = 0; o < 64; ++o) {
            float val = tanhf(acc[o]) * dX[(size_t)o*VD + v];
            outp[(size_t)o*VD + v] = zw[(size_t)o*VD + v] + 0.5f*(k1in[(size_t)o*VD + v] + val);
        }
    }
}

extern "C" void kernel_launch(void* const* d_in, const int* in_sizes, int n_in,
                              void* d_out, int out_size, void* d_ws, size_t ws_size,
                              hipStream_t stream)
{
    (void)in_sizes; (void)n_in; (void)out_size; (void)ws_size;
    const float* fast_logits = (const float*)d_in[0];
    const float* slow_logits = (const float*)d_in[1];
    const float* ego         = (const float*)d_in[2];
    const float* fenc_w      = (const float*)d_in[3];
    const float* fenc_b      = (const float*)d_in[4];
    const float* senc_w      = (const float*)d_in[5];
    const float* senc_b      = (const float*)d_in[6];
    const float* ctrl_w      = (const float*)d_in[7];
    const float* ctrl_b      = (const float*)d_in[8];
    const float* gin_w       = (const float*)d_in[9];
    const float* gin_b       = (const float*)d_in[10];
    const float* gbody_w     = (const float*)d_in[11];
    const float* gbody_b     = (const float*)d_in[12];
    const float* ggn_s       = (const float*)d_in[13];
    const float* ggn_b       = (const float*)d_in[14];
    const float* goutw       = (const float*)d_in[15];
    const float* goutb       = (const float*)d_in[16];
    const float* dec_w       = (const float*)d_in[17];
    const float* dec_b       = (const float*)d_in[18];
    const int*   ts          = (const int*)d_in[19];
    float* out = (float*)d_out;

    float* ws = (float*)d_ws;
    size_t off = 0;
    float* slotA = ws + off; off += (size_t)64*VD;
    float* slotB = ws + off; off += (size_t)64*VD;
    float* zbuf  = ws + off; off += (size_t)64*VD;
    float* zw    = ws + off; off += (size_t)64*VD;
    float* fadv  = ws + off; off += (size_t)64*VD;   // reused as k1
    float* dX    = ws + off; off += (size_t)64*VD;
    ushort16* hcl = (ushort16*)(ws + off); off += (size_t)16*VD;   // 32ch bf16 CL
    ushort16* ccl = (ushort16*)(ws + off); off += (size_t)16*VD;   // 32ch bf16 CL
    ushort16* zcl = (ushort16*)(ws + off); off += (size_t)32*VD;   // 64ch bf16 CL
    float* tinvs = ws + off; off += 48;
    float* dtau  = ws + off; off += 4;
    float* sums  = ws + off; off += 144;
    float* sqs   = ws + off; off += 144;
    float* fencT = ws + off; off += 64*18*27;
    float* sencT = ws + off; off += 64*18*27;
    float* ginT  = ws + off; off += 32*128;
    float* goutT = ws + off; off += 64*32;
    float* ctrlT = ws + off; off += 64*65 + 3;       // keep 16B alignment after
    ushort16* bApack = (ushort16*)(ws + off); off += 3*27648/2;
    ushort16* dApack = (ushort16*)(ws + off); off += 55296/2;
    float* k1 = fadv;

    prep_kernel<<<1, 256, 0, stream>>>(ego, ts, tinvs, dtau, sums, sqs);
    t3_kernel<<<122, 256, 0, stream>>>(fenc_w, fencT, 64, 18);
    t3_kernel<<<122, 256, 0, stream>>>(senc_w, sencT, 64, 18);
    t1_kernel<<<16, 256, 0, stream>>>(gin_w, ginT, 32, 128);
    t1_kernel<<<8, 256, 0, stream>>>(goutw, goutT, 64, 32);
    t1_kernel<<<17, 256, 0, stream>>>(ctrl_w, ctrlT, 64, 65);
    packA_body_kernel<<<dim3(108, 3), 256, 0, stream>>>(gbody_w, bApack);
    packA_dec_kernel<<<216, 256, 0, stream>>>(dec_w, dApack);

    dim3 encg(157, 16);
    dim3 gsp(VD/256);       // 625
    dim3 c1g4(625, 4);

    enc2_kernel<<<encg, 64, 0, stream>>>(fast_logits + (size_t)0*NCL*VF, fencT, fenc_b, slotA, nullptr);
    enc2_kernel<<<encg, 64, 0, stream>>>(fast_logits + (size_t)1*NCL*VF, fencT, fenc_b, slotB, nullptr);
    enc2_kernel<<<encg, 64, 0, stream>>>(slow_logits, sencT, senc_b, zbuf, slotA);

    int use = 0;
    for (int k = 0; k < 3; ++k) {
        float* fk = (k & 1) ? slotB : slotA;
        float* ft = (k & 1) ? slotA : slotB;
        warp_kernel<<<dim3(VD/256, 8), 256, 0, stream>>>(zbuf, fk, tinvs + k*16, zw, fadv);
        ctrl2_kernel<<<c1g4, 64, 0, stream>>>(ft, fadv, ctrlT, ctrl_b, dtau + k, dX);
        for (int half = 0; half < 2; ++half) {
            if (half == 0) gin3_kernel<<<gsp, 256, 0, stream>>>(zw, nullptr, fadv, ginT, gin_b, hcl);
            else           gin3_kernel<<<gsp, 256, 0, stream>>>(zw, k1, ft, ginT, gin_b, hcl);
            for (int i = 0; i < 3; ++i) {
                if (i == 0) body3_kernel<1><<<625, 256, 0, stream>>>(hcl, bApack + (size_t)0*27648, gbody_b + 0,  ccl);
                if (i == 1) body3_kernel<2><<<625, 256, 0, stream>>>(hcl, bApack + (size_t)1*27648, gbody_b + 32, ccl);
                if (i == 2) body3_kernel<3><<<625, 256, 0, stream>>>(hcl, bApack + (size_t)2*27648, gbody_b + 64, ccl);
                gnred3_kernel<<<80, 256, 0, stream>>>(ccl, sums + use*8, sqs + use*8);
                gnapply3_kernel<<<gsp, 256, 0, stream>>>(ccl, hcl, ggn_s + i*32, ggn_b + i*32,
                                                         sums + use*8, sqs + use*8);
                ++use;
            }
            if (half == 0) gout3_kernel<<<gsp, 256, 0, stream>>>(hcl, goutT, goutb, dX, nullptr, nullptr, k1, 0);
            else           gout3_kernel<<<gsp, 256, 0, stream>>>(hcl, goutT, goutb, dX, k1, zw, zbuf, 1);
        }
        if (k == 0) enc2_kernel<<<encg, 64, 0, stream>>>(fast_logits + (size_t)2*NCL*VF, fencT, fenc_b, slotA, nullptr);
        if (k == 1) enc2_kernel<<<encg, 64, 0, stream>>>(fast_logits + (size_t)3*NCL*VF, fencT, fenc_b, slotB, nullptr);
    }

    tocl64_kernel<<<2500, 64, 0, stream>>>(zbuf, zcl);
    dec3_kernel<<<2500, 256, 0, stream>>>(zcl, dApack, dec_b, fast_logits + (size_t)3*NCL*VF, out);
}